// Round 6
// baseline (18668.108 us; speedup 1.0000x reference)
//
#include <hip/hip_runtime.h>
#include <hip/hip_fp16.h>
#include <stdint.h>

// Gated LSTM: B=64, T=2048, I=128, H=256, O=1.
// R6: cut L3-coherence round trips (the real bottleneck per R5's WRITE_SIZE
// evidence: agent-scope atomics are write-through to the Infinity Cache
// regardless of XCD locality). 16 WGs = 8 batch-groups x 2 N-slices:
// ONE partner per WG (was 3), j-range 128 (512 z-rows), weights 384
// regs/thread (f16 MFMA B-frags; allocator splits across AGPR+VGPR in the
// unified file). Poll-hiding window doubled: x-part + own-half-h MFMAs
// (64/wave) run between poll issue and poll check. Publish volume halved.
// Exchange: tag-embedded {t+1 : 2xf16} relaxed agent atomics, double-
// buffered by t&1 (monotone tags; 0xAA ws poison never aliases a tag).

#define NT 2048
#define NI 128
#define NH 256
#define HBUF 8192   // uint64 words per buffer: 16 regions x 512

typedef _Float16 h8_t __attribute__((ext_vector_type(8)));
typedef _Float16 h4_t __attribute__((ext_vector_type(4)));
typedef _Float16 h2_t __attribute__((ext_vector_type(2)));
typedef float f4_t __attribute__((ext_vector_type(4)));

__device__ __forceinline__ float sigm(float x) {
  return __builtin_amdgcn_rcpf(1.f + __expf(-x));
}
__device__ __forceinline__ float tanh_f(float x) {
  return 1.f - 2.f * __builtin_amdgcn_rcpf(1.f + __expf(2.f * x));
}
__device__ __forceinline__ _Float16 b2h(uint32_t u) {
  return __builtin_bit_cast(_Float16, (uint16_t)(u & 0xffffu));
}

// lgkmcnt(0) only (vmcnt=63, expcnt=7 untouched): imm = 0xC07F
#define BAR() do {                                   \
    __asm__ __volatile__("" ::: "memory");           \
    __builtin_amdgcn_s_waitcnt(0xC07F);              \
    __builtin_amdgcn_s_barrier();                    \
    __asm__ __volatile__("" ::: "memory");           \
  } while (0)

#define AL(P) __hip_atomic_load((P), __ATOMIC_RELAXED, __HIP_MEMORY_SCOPE_AGENT)
#define AS(P, V) __hip_atomic_store((P), (V), __ATOMIC_RELAXED, __HIP_MEMORY_SCOPE_AGENT)

// ex (uint64): [buf2][region16 x 512]; region = g*2+p; word = m*64 + jw
// (jw = j_local/2, 2 f16 per word, tag t+1 in high 32).

__launch_bounds__(256, 1)
__global__ void lstm_persist(
    const float* __restrict__ xd, const float* __restrict__ w,
    const float* __restrict__ W_ih, const float* __restrict__ b_ih,
    const float* __restrict__ W_hh, const float* __restrict__ b_hh,
    const float* __restrict__ W_out, const float* __restrict__ b_out,
    float* __restrict__ out, uint64_t* ex)
{
  const int bid = blockIdx.x;
  const int g = bid & 7;        // batch group (8 groups x 8 batches)
  const int p = bid >> 3;       // N-slice 0/1 (j-range 128); partner bid = g+(1-p)*8
  const int tid = threadIdx.x;
  const int lane = tid & 63;
  const int wv = tid >> 6;      // wave 0..3
  const int q  = lane >> 4;     // 0..3
  const int cc = lane & 15;

  // A-tile: [m 16][x 0..127 | h buf0 128..383 | h buf1 384..639 | pad]
  __shared__ _Float16 Alds[16][648];
  __shared__ float S[8];
  for (int i = tid; i < 16 * 648; i += 256) (&Alds[0][0])[i] = (_Float16)0.f;

  // ---- W B-fragments: wave wv owns jc in {2wv, 2wv+1}, all 4 gates ----
  // z-row R = gate*256 + p*128 + jc*16 + cc ; k = kt*32 + q*8
  h8_t wf[2][4][12];
  float bias[2][4];
  for (int e2 = 0; e2 < 2; ++e2) {
    int jg = p * 128 + (2 * wv + e2) * 16 + cc;
    for (int gate = 0; gate < 4; ++gate) {
      bias[e2][gate] = b_ih[gate * NH + jg] + b_hh[gate * NH + jg];
      int R = gate * NH + jg;
      for (int kt = 0; kt < 12; ++kt) {
        int k = kt * 32 + q * 8;
        const float* s = (k < NI) ? (W_ih + (size_t)R * NI + k)
                                  : (W_hh + (size_t)R * NH + (k - NI));
        f4_t lo = *(const f4_t*)s;
        f4_t hi = *(const f4_t*)(s + 4);
        h8_t hh;
        hh[0] = (_Float16)lo[0]; hh[1] = (_Float16)lo[1];
        hh[2] = (_Float16)lo[2]; hh[3] = (_Float16)lo[3];
        hh[4] = (_Float16)hi[0]; hh[5] = (_Float16)hi[1];
        hh[6] = (_Float16)hi[2]; hh[7] = (_Float16)hi[3];
        wf[e2][gate][kt] = hh;
      }
    }
  }

  const int myreg = (g * 2 + p) * 512;
  const int pareg = (g * 2 + (1 - p)) * 512;
  // poll identity: thread owns partner words 2*tid, 2*tid+1 (same m)
  const int pm  = tid >> 5;        // m of both words
  const int pjw = (2 * tid) & 63;  // jw of first word (even)
  // epilogue m identity after q>=2 spread
  const int m0 = (q < 2) ? q * 4 : (q - 2) * 4 + 2;

  // x prefetch: thread stages row m=tid>>5, cols (tid&31)*4 .. +3
  const int xb = tid >> 5, xc = (tid & 31) * 4;
  const size_t xrow = ((size_t)(g * 8 + xb) * NT) * NI + xc;
  f4_t xa = *(const f4_t*)(xd + xrow);
  f4_t wa = *(const f4_t*)(w + xrow);

  float cst[4] = {0.f, 0.f, 0.f, 0.f};
  float hval[4] = {0.f, 0.f, 0.f, 0.f};

  __syncthreads();   // Alds zeros staged (h^0 = 0 in both buffers)

  for (int t = 0; t < NT; ++t) {
    // ---- issue partner polls (checked after 64 hiding MFMAs) ----
    uint64_t v0 = 0, v1 = 0;
    const uint64_t* pb = ex + (size_t)(t & 1) * HBUF + pareg;
    if (t > 0) { v0 = AL(pb + 2 * tid); v1 = AL(pb + 2 * tid + 1); }

    // ---- stage gated x_t from prefetched regs; prefetch t+1 ----
    {
      h4_t gx;
      gx[0] = (_Float16)(xa[0] * sigm(wa[0]));
      gx[1] = (_Float16)(xa[1] * sigm(wa[1]));
      gx[2] = (_Float16)(xa[2] * sigm(wa[2]));
      gx[3] = (_Float16)(xa[3] * sigm(wa[3]));
      *(h4_t*)(&Alds[xb][xc]) = gx;
      size_t xo = xrow + (size_t)((t + 1 < NT) ? t + 1 : NT - 1) * NI;
      xa = *(const f4_t*)(xd + xo);
      wa = *(const f4_t*)(w + xo);
    }
    BAR();                             // barrier A: x staged

    // ---- phase 1: x-part (kt 0..3) + own-half h (4 kt) = 64 MFMAs/wave ----
    const int hc = 128 + (t & 1) * 256;
    f4_t acc[2][4];
    #pragma unroll
    for (int e2 = 0; e2 < 2; ++e2)
      #pragma unroll
      for (int gate = 0; gate < 4; ++gate) {
        float bv = bias[e2][gate];
        acc[e2][gate] = (f4_t){bv, bv, bv, bv};
      }
    #pragma unroll
    for (int kt = 0; kt < 4; ++kt) {
      h8_t af = *(const h8_t*)(&Alds[cc][kt * 32 + q * 8]);
      #pragma unroll
      for (int e2 = 0; e2 < 2; ++e2)
        #pragma unroll
        for (int gate = 0; gate < 4; ++gate)
          acc[e2][gate] = __builtin_amdgcn_mfma_f32_16x16x32_f16(
              af, wf[e2][gate][kt], acc[e2][gate], 0, 0, 0);
    }
    const int oc = hc + p * 128;       // own h half
    #pragma unroll
    for (int kt = 0; kt < 4; ++kt) {
      h8_t af = *(const h8_t*)(&Alds[cc][oc + kt * 32 + q * 8]);
      #pragma unroll
      for (int e2 = 0; e2 < 2; ++e2)
        #pragma unroll
        for (int gate = 0; gate < 4; ++gate)
          acc[e2][gate] = __builtin_amdgcn_mfma_f32_16x16x32_f16(
              af, wf[e2][gate][4 + p * 4 + kt], acc[e2][gate], 0, 0, 0);
    }

    // ---- check polls, stage partner half ----
    const int pc = hc + (1 - p) * 128;
    if (t > 0) {
      bool n0 = true, n1 = true;
      while (n0 || n1) {
        if (n0) {
          if ((unsigned)(v0 >> 32) == (unsigned)t) {
            uint32_t a = (uint32_t)v0;
            h2_t hp; hp[0] = b2h(a); hp[1] = b2h(a >> 16);
            *(h2_t*)(&Alds[pm][pc + pjw * 2]) = hp;
            n0 = false;
          } else v0 = AL(pb + 2 * tid);
        }
        if (n1) {
          if ((unsigned)(v1 >> 32) == (unsigned)t) {
            uint32_t a = (uint32_t)v1;
            h2_t hp; hp[0] = b2h(a); hp[1] = b2h(a >> 16);
            *(h2_t*)(&Alds[pm][pc + (pjw + 1) * 2]) = hp;
            n1 = false;
          } else v1 = AL(pb + 2 * tid + 1);
        }
      }
    }
    BAR();                             // barrier B: partner h staged

    // ---- phase 2: partner-half h (4 kt) = 32 MFMAs/wave ----
    #pragma unroll
    for (int kt = 0; kt < 4; ++kt) {
      h8_t af = *(const h8_t*)(&Alds[cc][pc + kt * 32 + q * 8]);
      #pragma unroll
      for (int e2 = 0; e2 < 2; ++e2)
        #pragma unroll
        for (int gate = 0; gate < 4; ++gate)
          acc[e2][gate] = __builtin_amdgcn_mfma_f32_16x16x32_f16(
              af, wf[e2][gate][4 + (1 - p) * 4 + kt], acc[e2][gate], 0, 0, 0);
    }

    // ---- spread epilogue: 4 (m,j) pairs per lane on all 64 lanes ----
    const int hc1 = 128 + ((t + 1) & 1) * 256;
    uint64_t* ob = ex + (size_t)((t + 1) & 1) * HBUF + myreg;
    #pragma unroll
    for (int e2 = 0; e2 < 2; ++e2) {
      float z[2][4];
      #pragma unroll
      for (int gate = 0; gate < 4; ++gate) {
        float a2 = __shfl_xor(acc[e2][gate][2], 32, 64);
        float a3 = __shfl_xor(acc[e2][gate][3], 32, 64);
        z[0][gate] = (q < 2) ? acc[e2][gate][0] : a2;
        z[1][gate] = (q < 2) ? acc[e2][gate][1] : a3;
      }
      const int jl = (2 * wv + e2) * 16 + cc;
      #pragma unroll
      for (int eh = 0; eh < 2; ++eh) {
        int idx = e2 * 2 + eh;
        cst[idx] = sigm(z[eh][1]) * cst[idx] + sigm(z[eh][0]) * tanh_f(z[eh][2]);
        hval[idx] = sigm(z[eh][3]) * tanh_f(cst[idx]);
        float hn = __shfl_xor(hval[idx], 1, 64);   // neighbor j (cc^1)
        if (!(cc & 1)) {
          int m = m0 + eh;
          h2_t hp; hp[0] = (_Float16)hval[idx]; hp[1] = (_Float16)hn;
          *(h2_t*)(&Alds[m][hc1 + p * 128 + jl]) = hp;
          uint32_t pk = __builtin_bit_cast(uint32_t, hp);
          AS(ob + m * 64 + (jl >> 1),
             (((uint64_t)(unsigned)(t + 1)) << 32) | pk);
        }
      }
    }
    // next step's barrier A orders epilogue LDS writes vs MFMA reads
  }

  // ---- output: out[b] = h_T . W_out + b_out (group pair covers full H) ----
  if (tid < 8) S[tid] = 0.f;
  BAR();
  {
    // own-half contribution (lane -> 4 pairs; e2-sum shares m)
    float vo[2] = {0.f, 0.f};
    #pragma unroll
    for (int e2 = 0; e2 < 2; ++e2) {
      int jl = (2 * wv + e2) * 16 + cc;
      vo[0] += hval[e2 * 2 + 0] * W_out[p * 128 + jl];
      vo[1] += hval[e2 * 2 + 1] * W_out[p * 128 + jl];
    }
    #pragma unroll
    for (int off = 1; off < 16; off <<= 1) {   // reduce over cc
      vo[0] += __shfl_xor(vo[0], off, 64);
      vo[1] += __shfl_xor(vo[1], off, 64);
    }
    if (cc == 0) {
      atomicAdd(&S[m0], vo[0]);
      atomicAdd(&S[m0 + 1], vo[1]);
    }
    // partner-half finals (tag NT, buf 0 since NT is even)
    const uint64_t* pb = ex + pareg;
    uint64_t v0 = AL(pb + 2 * tid), v1 = AL(pb + 2 * tid + 1);
    while ((unsigned)(v0 >> 32) != (unsigned)NT) v0 = AL(pb + 2 * tid);
    while ((unsigned)(v1 >> 32) != (unsigned)NT) v1 = AL(pb + 2 * tid + 1);
    const float* wp = W_out + (1 - p) * 128;
    float c = (float)b2h((uint32_t)v0)       * wp[pjw * 2]
            + (float)b2h((uint32_t)v0 >> 16) * wp[pjw * 2 + 1]
            + (float)b2h((uint32_t)v1)       * wp[(pjw + 1) * 2]
            + (float)b2h((uint32_t)v1 >> 16) * wp[(pjw + 1) * 2 + 1];
    atomicAdd(&S[pm], c);
  }
  BAR();
  if (p == 0 && tid < 8) out[g * 8 + tid] = S[tid] + b_out[0];
}

extern "C" void kernel_launch(void* const* d_in, const int* in_sizes, int n_in,
                              void* d_out, int out_size, void* d_ws, size_t ws_size,
                              hipStream_t stream) {
  (void)in_sizes; (void)n_in; (void)out_size; (void)ws_size;
  const float* xd    = (const float*)d_in[0];
  const float* w     = (const float*)d_in[1];
  const float* W_ih  = (const float*)d_in[2];
  const float* b_ih  = (const float*)d_in[3];
  const float* W_hh  = (const float*)d_in[4];
  const float* b_hh  = (const float*)d_in[5];
  const float* W_out = (const float*)d_in[6];
  const float* b_out = (const float*)d_in[7];
  // ws: 2*HBUF uint64 = 128 KB tagged-h exchange. No memset: 0xAA poison
  // tag (0xAAAAAAAA) never equals a valid tag (<= 2048).
  uint64_t* ex = (uint64_t*)d_ws;
  lstm_persist<<<dim3(16), dim3(256), 0, stream>>>(
      xd, w, W_ih, b_ih, W_hh, b_hh, W_out, b_out, (float*)d_out, ex);
}